// Round 1
// baseline (130220.496 us; speedup 1.0000x reference)
//
#include <hip/hip_runtime.h>
#include <hip/hip_cooperative_groups.h>

namespace cg = cooperative_groups;

#define T_STEPS 4096
#define DIN     512
#define R_DIM   4096
#define DOUT    512
#define NINT    (R_DIM + DIN)   // 4608
#define LEAKF   0.9f

// ---------------------------------------------------------------------------
// Persistent ESN scan. 256 blocks (1 per CU) x 512 threads (8 waves).
// Block c owns state rows [16c, 16c+16). Wave w owns rows 16c+2w, 16c+2w+1.
// Wres rows live in registers: w0[j]/w1[j] = Wres[row][j*64 + lane].
// Input projection u_i = x_i . Win[row] + b is computed on the fly (Win rows
// also in registers), so no u buffer / GEMM is needed.
// ---------------------------------------------------------------------------
__global__ __launch_bounds__(512) void esn_scan(
    const float* __restrict__ x,      // (T, DIN)
    const float* __restrict__ Win_w,  // (R, DIN)
    const float* __restrict__ Win_b,  // (R)
    const float* __restrict__ Wres,   // (R, R)
    float* __restrict__ states)       // (T, R)
{
    const int wave = threadIdx.x >> 6;
    const int lane = threadIdx.x & 63;
    const int row0 = (blockIdx.x << 4) + (wave << 1);
    const int row1 = row0 + 1;

    // --- load weights into registers (one-time, ~64 MB across chip) ---
    float w0[64], w1[64];
    {
        const float* p0 = Wres + (size_t)row0 * R_DIM + lane;
        const float* p1 = Wres + (size_t)row1 * R_DIM + lane;
#pragma unroll
        for (int j = 0; j < 64; ++j) { w0[j] = p0[j * 64]; w1[j] = p1[j * 64]; }
    }
    float win0[8], win1[8];
    {
        const float* p0 = Win_w + (size_t)row0 * DIN + lane;
        const float* p1 = Win_w + (size_t)row1 * DIN + lane;
#pragma unroll
        for (int j = 0; j < 8; ++j) { win0[j] = p0[j * 64]; win1[j] = p1[j * 64]; }
    }
    const float bias0 = Win_b[row0];
    const float bias1 = Win_b[row1];

    cg::grid_group grid = cg::this_grid();

    float s_old0 = 0.0f, s_old1 = 0.0f;   // only lane 0's copy is meaningful

    for (int i = 0; i < T_STEPS; ++i) {
        if (i > 0) grid.sync();   // wait until states[i-1] fully written+visible

        // input projection partials
        float a0 = 0.0f, a1 = 0.0f;
        {
            const float* xr = x + (size_t)i * DIN + lane;
#pragma unroll
            for (int j = 0; j < 8; ++j) {
                float xv = xr[j * 64];
                a0 += win0[j] * xv;
                a1 += win1[j] * xv;
            }
        }

        // reservoir matvec partials (skip for i==0: s0 = tanh(u0))
        if (i > 0) {
            const float* sp = states + (size_t)(i - 1) * R_DIM + lane;
            float a0b = 0.0f, a1b = 0.0f;
#pragma unroll
            for (int j = 0; j < 64; j += 2) {
                float sva = sp[j * 64];
                float svb = sp[(j + 1) * 64];
                a0  += w0[j] * sva;
                a1  += w1[j] * sva;
                a0b += w0[j + 1] * svb;
                a1b += w1[j + 1] * svb;
            }
            a0 += a0b;
            a1 += a1b;
        }

        // butterfly reduce across the 64-lane wave
#pragma unroll
        for (int m = 32; m >= 1; m >>= 1) {
            a0 += __shfl_xor(a0, m, 64);
            a1 += __shfl_xor(a1, m, 64);
        }

        if (lane == 0) {
            float pre0 = a0 + bias0;
            float pre1 = a1 + bias1;
            float xi0 = tanhf(pre0);
            float xi1 = tanhf(pre1);
            float sn0, sn1;
            if (i == 0) { sn0 = xi0; sn1 = xi1; }
            else {
                sn0 = (1.0f - LEAKF) * s_old0 + LEAKF * xi0;
                sn1 = (1.0f - LEAKF) * s_old1 + LEAKF * xi1;
            }
            states[(size_t)i * R_DIM + row0] = sn0;
            states[(size_t)i * R_DIM + row1] = sn1;
            s_old0 = sn0;
            s_old1 = sn1;
        }
    }
}

// ---------------------------------------------------------------------------
// Readout: y = [x | states] @ Wout^T + b.  fp32, 64x64 tile, K-step 64.
// Both A and B are row-major along K (NT gemm: dot of rows).
// ---------------------------------------------------------------------------
__global__ __launch_bounds__(256) void out_gemm(
    const float* __restrict__ x,       // (T, DIN)
    const float* __restrict__ states,  // (T, R)
    const float* __restrict__ Wout_w,  // (DOUT, NINT)
    const float* __restrict__ Wout_b,  // (DOUT)
    float* __restrict__ y)             // (T, DOUT)
{
    __shared__ float As[64][68];
    __shared__ float Bs[64][68];

    const int i0 = blockIdx.x << 6;
    const int o0 = blockIdx.y << 6;
    const int tid = threadIdx.x;
    const int tx = tid & 15, ty = tid >> 4;

    float acc[4][4] = {};

    for (int k0 = 0; k0 < NINT; k0 += 64) {
#pragma unroll
        for (int q = 0; q < 4; ++q) {
            int f  = tid + (q << 8);      // float4 slot 0..1023
            int r  = f >> 4;              // 0..63
            int c4 = (f & 15) << 2;       // 0,4,...,60
            const float* asrc;
            if (k0 < DIN) asrc = x + (size_t)(i0 + r) * DIN + (k0 + c4);
            else          asrc = states + (size_t)(i0 + r) * R_DIM + (k0 - DIN + c4);
            *(float4*)&As[r][c4] = *(const float4*)asrc;
            const float* bsrc = Wout_w + (size_t)(o0 + r) * NINT + (k0 + c4);
            *(float4*)&Bs[r][c4] = *(const float4*)bsrc;
        }
        __syncthreads();

#pragma unroll 16
        for (int kk = 0; kk < 64; ++kk) {
            float a[4], b[4];
#pragma unroll
            for (int q = 0; q < 4; ++q) a[q] = As[(ty << 2) + q][kk];
#pragma unroll
            for (int p = 0; p < 4; ++p) b[p] = Bs[(tx << 2) + p][kk];
#pragma unroll
            for (int q = 0; q < 4; ++q)
#pragma unroll
                for (int p = 0; p < 4; ++p) acc[q][p] += a[q] * b[p];
        }
        __syncthreads();
    }

#pragma unroll
    for (int q = 0; q < 4; ++q) {
        int row = i0 + (ty << 2) + q;
#pragma unroll
        for (int p = 0; p < 4; ++p) {
            int col = o0 + (tx << 2) + p;
            y[(size_t)row * DOUT + col] = acc[q][p] + Wout_b[col];
        }
    }
}

extern "C" void kernel_launch(void* const* d_in, const int* in_sizes, int n_in,
                              void* d_out, int out_size, void* d_ws, size_t ws_size,
                              hipStream_t stream) {
    const float* x      = (const float*)d_in[0];
    const float* Win_w  = (const float*)d_in[1];
    const float* Win_b  = (const float*)d_in[2];
    const float* Wres_w = (const float*)d_in[3];
    const float* Wout_w = (const float*)d_in[4];
    const float* Wout_b = (const float*)d_in[5];
    float* y = (float*)d_out;

    float* states = (float*)d_ws;   // T_STEPS * R_DIM * 4 = 64 MB

    {
        void* args[] = { (void*)&x, (void*)&Win_w, (void*)&Win_b,
                         (void*)&Wres_w, (void*)&states };
        hipLaunchCooperativeKernel((void*)esn_scan, dim3(256), dim3(512),
                                   args, 0, stream);
    }
    {
        dim3 grid(T_STEPS / 64, DOUT / 64);
        out_gemm<<<grid, 256, 0, stream>>>(x, states, Wout_w, Wout_b, y);
    }
}

// Round 2
// 18234.518 us; speedup vs baseline: 7.1414x; 7.1414x over previous
//
#include <hip/hip_runtime.h>

#define T_STEPS 4096
#define DIN     512
#define R_DIM   4096
#define DOUT    512
#define NINT    (R_DIM + DIN)   // 4608
#define LEAKF   0.9f
#define NBLK    256
#define NTHR    512

typedef float f32x4 __attribute__((ext_vector_type(4)));

// Zero the inter-block flags each call (graph replays reuse d_ws).
__global__ void init_flags(int* flags) { flags[threadIdx.x] = 0; }

// ---------------------------------------------------------------------------
// Persistent ESN scan + fused readout. 256 blocks x 512 threads (cooperative
// launch guarantees co-residency; sync is a custom flag barrier, not
// grid.sync). Block b owns state rows [16b,16b+16) (wave w: rows 16b+2w,
// 16b+2w+1) and output rows {2b, 2b+1}.
//
// Weights in registers: w0[j]/w1[j] = Wres[row][lane + 64*j]  (128 VGPRs).
// Cross-block exchange: comm[2][4096] in d_ws, written with sc0|sc1
// (write-through to the coherent point), read back the same way; per-block
// flag = last completed step + 1.
// ---------------------------------------------------------------------------
__global__ __launch_bounds__(NTHR, 2) void esn_scan(
    const float* __restrict__ x,       // (T, DIN)
    const float* __restrict__ Win_w,   // (R, DIN)
    const float* __restrict__ Win_b,   // (R)
    const float* __restrict__ Wres,    // (R, R)
    const float* __restrict__ Wout_w,  // (DOUT, NINT)
    const float* __restrict__ Wout_b,  // (DOUT)
    float* __restrict__ y,             // (T, DOUT)
    float* __restrict__ comm,          // 2 * R_DIM floats (exchange, d_ws)
    int* __restrict__ flags)           // NBLK ints (d_ws)
{
    const int tid  = threadIdx.x;
    const int wave = tid >> 6;
    const int lane = tid & 63;
    const int bid  = blockIdx.x;
    const int row0 = (bid << 4) + (wave << 1);
    const int row1 = row0 + 1;

    __shared__ float s_lds[R_DIM];          // 16 KB: s_{i-1}
    __shared__ float wout_lds[2 * NINT];    // 36.9 KB: 2 rows of Wout
    __shared__ float red[8][2];

    // --- stage this block's 2 Wout rows into LDS (once) ---
    {
        const float* wsrc = Wout_w + (size_t)(bid << 1) * NINT;
        for (int idx = tid; idx < 2 * NINT; idx += NTHR)
            wout_lds[idx] = wsrc[idx];
    }

    // --- Wres rows into registers (once) ---
    float w0[64], w1[64];
    {
        const float* p0 = Wres + (size_t)row0 * R_DIM + lane;
        const float* p1 = Wres + (size_t)row1 * R_DIM + lane;
#pragma unroll
        for (int j = 0; j < 64; ++j) { w0[j] = p0[j * 64]; w1[j] = p1[j * 64]; }
    }
    float win0[8], win1[8];
    {
        const float* p0 = Win_w + (size_t)row0 * DIN + lane;
        const float* p1 = Win_w + (size_t)row1 * DIN + lane;
#pragma unroll
        for (int j = 0; j < 8; ++j) { win0[j] = p0[j * 64]; win1[j] = p1[j * 64]; }
    }
    const float bias0 = Win_b[row0];
    const float bias1 = Win_b[row1];

    float s_old0 = 0.f, s_old1 = 0.f;   // lane 0's copy is authoritative

    // ---------------- step 0: s0 = tanh(Win x0 + b) ----------------
    {
        float a0 = 0.f, a1 = 0.f;
        const float* xr = x + lane;
#pragma unroll
        for (int j = 0; j < 8; ++j) {
            float xv = xr[j * 64];
            a0 += win0[j] * xv; a1 += win1[j] * xv;
        }
#pragma unroll
        for (int m = 32; m >= 1; m >>= 1) {
            a0 += __shfl_xor(a0, m, 64);
            a1 += __shfl_xor(a1, m, 64);
        }
        if (lane == 0) {
            float sn0 = tanhf(a0 + bias0);
            float sn1 = tanhf(a1 + bias1);
            const float* d0 = comm + row0;   // buffer 0
            const float* d1 = comm + row1;
            asm volatile("global_store_dword %0, %1, off sc0 sc1" :: "v"(d0), "v"(sn0) : "memory");
            asm volatile("global_store_dword %0, %1, off sc0 sc1" :: "v"(d1), "v"(sn1) : "memory");
            asm volatile("s_waitcnt vmcnt(0)" ::: "memory");
            s_old0 = sn0; s_old1 = sn1;
        }
        __syncthreads();
        if (tid == 0)
            __hip_atomic_store(&flags[bid], 1, __ATOMIC_RELAXED, __HIP_MEMORY_SCOPE_AGENT);
    }

    // ---------------- steps 1..T-1 (+ epilogue i==T for y[T-1]) ----------------
    for (int i = 1; i <= T_STEPS; ++i) {
        // input projection for step i (issued before the barrier to hide latency)
        float a0 = 0.f, a1 = 0.f;
        if (i < T_STEPS) {
            const float* xr = x + (size_t)i * DIN + lane;
#pragma unroll
            for (int j = 0; j < 8; ++j) {
                float xv = xr[j * 64];
                a0 += win0[j] * xv; a1 += win1[j] * xv;
            }
        }

        // ---- barrier: wait until every block published step i-1 ----
        if (wave == 0) {
            const int* fp = flags + (lane << 2);
            int pend = 0xF;
            while (pend) {
#pragma unroll
                for (int q = 0; q < 4; ++q)
                    if ((pend >> q) & 1)
                        if (__hip_atomic_load(fp + q, __ATOMIC_RELAXED,
                                              __HIP_MEMORY_SCOPE_AGENT) >= i)
                            pend &= ~(1 << q);
                if (pend) __builtin_amdgcn_s_sleep(2);
            }
        }
        __syncthreads();

        // ---- stage s_{i-1} into LDS (coherent loads bypass stale L1/L2) ----
        {
            const float* src = comm + (size_t)((i - 1) & 1) * R_DIM + (tid << 3);
            f32x4 va, vb;
            asm volatile("global_load_dwordx4 %0, %2, off sc0 sc1\n\t"
                         "global_load_dwordx4 %1, %3, off sc0 sc1\n\t"
                         "s_waitcnt vmcnt(0)"
                         : "=&v"(va), "=&v"(vb)
                         : "v"(src), "v"(src + 4)
                         : "memory");
            *(f32x4*)&s_lds[tid << 3] = va;
            *(f32x4*)&s_lds[(tid << 3) + 4] = vb;
        }
        __syncthreads();

        // ---- fused readout: y[i-1] rows {2b, 2b+1} ----
        {
            float y0, y1;
            float xv = x[(size_t)(i - 1) * DIN + tid];
            y0 = wout_lds[tid] * xv;
            y1 = wout_lds[NINT + tid] * xv;
#pragma unroll
            for (int j = 0; j < 8; ++j) {
                float sv = s_lds[tid + j * NTHR];
                y0 += wout_lds[DIN + tid + j * NTHR] * sv;
                y1 += wout_lds[NINT + DIN + tid + j * NTHR] * sv;
            }
#pragma unroll
            for (int m = 32; m >= 1; m >>= 1) {
                y0 += __shfl_xor(y0, m, 64);
                y1 += __shfl_xor(y1, m, 64);
            }
            if (lane == 0) { red[wave][0] = y0; red[wave][1] = y1; }
            __syncthreads();
            if (tid < 2) {
                float s = 0.f;
#pragma unroll
                for (int w = 0; w < 8; ++w) s += red[w][tid];
                y[(size_t)(i - 1) * DOUT + (bid << 1) + tid] =
                    s + Wout_b[(bid << 1) + tid];
            }
        }

        if (i == T_STEPS) break;

        // ---- reservoir matvec from LDS, weights in registers ----
#pragma unroll
        for (int j = 0; j < 64; ++j) {
            float sv = s_lds[lane + (j << 6)];
            a0 += w0[j] * sv;
            a1 += w1[j] * sv;
        }
#pragma unroll
        for (int m = 32; m >= 1; m >>= 1) {
            a0 += __shfl_xor(a0, m, 64);
            a1 += __shfl_xor(a1, m, 64);
        }
        if (lane == 0) {
            float xi0 = tanhf(a0 + bias0);
            float xi1 = tanhf(a1 + bias1);
            float sn0 = (1.f - LEAKF) * s_old0 + LEAKF * xi0;
            float sn1 = (1.f - LEAKF) * s_old1 + LEAKF * xi1;
            float* dstb = comm + (size_t)(i & 1) * R_DIM;
            const float* d0 = dstb + row0;
            const float* d1 = dstb + row1;
            asm volatile("global_store_dword %0, %1, off sc0 sc1" :: "v"(d0), "v"(sn0) : "memory");
            asm volatile("global_store_dword %0, %1, off sc0 sc1" :: "v"(d1), "v"(sn1) : "memory");
            asm volatile("s_waitcnt vmcnt(0)" ::: "memory");
            s_old0 = sn0; s_old1 = sn1;
        }
        __syncthreads();   // all waves' coherent stores retired
        if (tid == 0)
            __hip_atomic_store(&flags[bid], i + 1, __ATOMIC_RELAXED, __HIP_MEMORY_SCOPE_AGENT);
    }
}

extern "C" void kernel_launch(void* const* d_in, const int* in_sizes, int n_in,
                              void* d_out, int out_size, void* d_ws, size_t ws_size,
                              hipStream_t stream) {
    const float* x      = (const float*)d_in[0];
    const float* Win_w  = (const float*)d_in[1];
    const float* Win_b  = (const float*)d_in[2];
    const float* Wres_w = (const float*)d_in[3];
    const float* Wout_w = (const float*)d_in[4];
    const float* Wout_b = (const float*)d_in[5];
    float* yp = (float*)d_out;

    float* comm = (float*)d_ws;                         // 2*4096 floats = 32 KB
    int* flags  = (int*)((char*)d_ws + 64 * 1024);      // 256 ints

    init_flags<<<1, NBLK, 0, stream>>>(flags);

    void* args[] = { (void*)&x, (void*)&Win_w, (void*)&Win_b, (void*)&Wres_w,
                     (void*)&Wout_w, (void*)&Wout_b, (void*)&yp,
                     (void*)&comm, (void*)&flags };
    hipLaunchCooperativeKernel((void*)esn_scan, dim3(NBLK), dim3(NTHR),
                               args, 0, stream);
}

// Round 3
// 12477.664 us; speedup vs baseline: 10.4363x; 1.4614x over previous
//
#include <hip/hip_runtime.h>

#define T_STEPS 4096
#define DIN     512
#define R_DIM   4096
#define DOUT    512
#define NINT    (R_DIM + DIN)   // 4608
#define NBLK    256
#define NTHR    512
#define NSLOT   2048            // 16B slots per buffer (2 values + 2 tags each)
#define LEAKF   0.9f

typedef float f32x4 __attribute__((ext_vector_type(4)));
typedef unsigned int u32;
typedef u32 u32x4 __attribute__((ext_vector_type(4)));

// Multi-value butterfly: returns full 64-lane sum of a_{lane&3} (10 shuffles).
__device__ __forceinline__ float wave_reduce4(float a0, float a1, float a2, float a3, int lane)
{
    a0 += __shfl_xor(a0, 1); a1 += __shfl_xor(a1, 1);
    a2 += __shfl_xor(a2, 1); a3 += __shfl_xor(a3, 1);
    float b0 = (lane & 1) ? a1 : a0;
    float b1 = (lane & 1) ? a3 : a2;
    b0 += __shfl_xor(b0, 2); b1 += __shfl_xor(b1, 2);
    float c = (lane & 2) ? b1 : b0;
    c += __shfl_xor(c, 4);
    c += __shfl_xor(c, 8);
    c += __shfl_xor(c, 16);
    c += __shfl_xor(c, 32);
    return c;
}

// Publisher (wave 0 only): lanes 0..15 hold the block's 16 new states in sn.
// Pack pairs into LL slots {s_even, tag, s_odd, tag} and store coherently.
__device__ __forceinline__ void publish16(float sn, int lane, int bid, int bufsel,
                                          u32 tag, u32x4* comm)
{
    float e = __shfl(sn, (lane & 7) << 1);
    float o = __shfl(sn, ((lane & 7) << 1) + 1);
    if (lane < 8) {
        u32x4 pkt;
        pkt.x = __float_as_uint(e); pkt.y = tag;
        pkt.z = __float_as_uint(o); pkt.w = tag;
        u32x4* dst = comm + bufsel * NSLOT + (bid << 3) + lane;
        asm volatile("global_store_dwordx4 %0, %1, off sc0 sc1"
                     :: "v"(dst), "v"(pkt) : "memory");
    }
}

// ---------------------------------------------------------------------------
// Persistent fused ESN. 256 blocks x 512 threads, 1 block/CU (cooperative).
// Block b owns rows [16b,16b+16). Wave pair p = waves {2p,2p+1} owns rows
// 4p..4p+3; wave 2p handles K in [0,2048), wave 2p+1 K in [2048,4096).
// Thread: 4 rows x 32 K-elems -> w[4][8] f32x4 in registers (128 VGPRs).
// ---------------------------------------------------------------------------
__global__ __launch_bounds__(NTHR, 2) void esn_fused(
    const float* __restrict__ x,       // (T, DIN)
    const float* __restrict__ Win_w,   // (R, DIN)
    const float* __restrict__ Win_b,   // (R)
    const float* __restrict__ Wres,    // (R, R)
    const float* __restrict__ Wout_w,  // (DOUT, NINT)
    const float* __restrict__ Wout_b,  // (DOUT)
    float* __restrict__ y,             // (T, DOUT)
    u32x4* __restrict__ comm)          // 2 * NSLOT slots (d_ws)
{
    const int tid  = threadIdx.x;
    const int wave = tid >> 6;
    const int lane = tid & 63;
    const int bid  = blockIdx.x;
    const int pair = wave >> 1;
    const int half = wave & 1;
    const int rbase = (bid << 4) + (pair << 2);

    __shared__ float s_lds[R_DIM];          // 16 KB
    __shared__ float wout_lds[2 * NINT];    // 36.9 KB
    __shared__ float red[8][4];
    __shared__ float red2[8][2];

    // ---- one-time staging ----
    {
        const float* wsrc = Wout_w + (size_t)(bid << 1) * NINT;
        for (int idx = tid; idx < 2 * NINT; idx += NTHR)
            wout_lds[idx] = wsrc[idx];
    }
    const float wb = (tid < 2) ? Wout_b[(bid << 1) + tid] : 0.f;

    f32x4 w[4][8];
    {
        const float* wp = Wres + (size_t)rbase * R_DIM + (half << 11) + (lane << 2);
#pragma unroll
        for (int r = 0; r < 4; ++r)
#pragma unroll
            for (int c = 0; c < 8; ++c)
                w[r][c] = *(const f32x4*)(wp + (size_t)r * R_DIM + (c << 8));
    }
    f32x4 win[4];
    {
        const float* wp = Win_w + (size_t)rbase * DIN + (half << 8) + (lane << 2);
#pragma unroll
        for (int r = 0; r < 4; ++r)
            win[r] = *(const f32x4*)(wp + (size_t)r * DIN);
    }
    float bias = 0.f, s_old = 0.f;
    if (wave == 0 && lane < 16) bias = Win_b[(bid << 4) + lane];

    float a0, a1, a2, a3;

    // ---- proj(0) ----
    {
        f32x4 xv = *(const f32x4*)(x + (half << 8) + (lane << 2));
        a0 = a1 = a2 = a3 = 0.f;
#pragma unroll
        for (int q = 0; q < 4; ++q) {
            a0 += win[0][q] * xv[q];
            a1 += win[1][q] * xv[q];
            a2 += win[2][q] * xv[q];
            a3 += win[3][q] * xv[q];
        }
    }
    // ---- publish step 0: s0 = tanh(u0), tag 1, buf 0 ----
    {
        float c_ = wave_reduce4(a0, a1, a2, a3, lane);
        if (lane < 4) red[wave][lane] = c_;
        __syncthreads();
        if (wave == 0) {
            float sn = 0.f;
            if (lane < 16) {
                int p2 = (lane >> 2) << 1;
                float val = red[p2][lane & 3] + red[p2 + 1][lane & 3] + bias;
                sn = tanhf(val);
                s_old = sn;
            }
            publish16(sn, lane, bid, 0, 1u, comm);
        }
    }
    // ---- proj(1) ----
    {
        f32x4 xv = *(const f32x4*)(x + DIN + (half << 8) + (lane << 2));
        a0 = a1 = a2 = a3 = 0.f;
#pragma unroll
        for (int q = 0; q < 4; ++q) {
            a0 += win[0][q] * xv[q];
            a1 += win[1][q] * xv[q];
            a2 += win[2][q] * xv[q];
            a3 += win[3][q] * xv[q];
        }
    }

    for (int i = 1; i <= T_STEPS; ++i) {
        // ---- stage s_{i-1}: poll LL slots (tag i), write to LDS ----
        {
            const u32x4* src = comm + (((i - 1) & 1) * NSLOT) + (tid << 2);
            const u32 tag = (u32)i;
            u32x4 q0, q1, q2, q3;
            for (;;) {
                asm volatile("global_load_dwordx4 %0, %1, off sc0 sc1\n\t"
                             "s_waitcnt vmcnt(0)"
                             : "=&v"(q0) : "v"(src) : "memory");
                if ((q0.y == tag) & (q0.w == tag)) {
                    asm volatile("global_load_dwordx4 %0, %3, off sc0 sc1\n\t"
                                 "global_load_dwordx4 %1, %4, off sc0 sc1\n\t"
                                 "global_load_dwordx4 %2, %5, off sc0 sc1\n\t"
                                 "s_waitcnt vmcnt(0)"
                                 : "=&v"(q1), "=&v"(q2), "=&v"(q3)
                                 : "v"(src + 1), "v"(src + 2), "v"(src + 3)
                                 : "memory");
                    u32 ok = (q1.y == tag) & (q1.w == tag) & (q2.y == tag) &
                             (q2.w == tag) & (q3.y == tag) & (q3.w == tag);
                    if (ok) break;
                }
                __builtin_amdgcn_s_sleep(1);
            }
            f32x4 lo, hi;
            lo[0] = __uint_as_float(q0.x); lo[1] = __uint_as_float(q0.z);
            lo[2] = __uint_as_float(q1.x); lo[3] = __uint_as_float(q1.z);
            hi[0] = __uint_as_float(q2.x); hi[1] = __uint_as_float(q2.z);
            hi[2] = __uint_as_float(q3.x); hi[3] = __uint_as_float(q3.z);
            *(f32x4*)&s_lds[tid << 3] = lo;
            *(f32x4*)&s_lds[(tid << 3) + 4] = hi;
        }
        __syncthreads();

        if (i < T_STEPS) {
            // ---- reservoir matvec (weights in regs, s from LDS via b128) ----
            {
                const f32x4* s4 = (const f32x4*)s_lds + (half << 9) + lane;
#pragma unroll
                for (int c = 0; c < 8; ++c) {
                    f32x4 sv = s4[c << 6];
#pragma unroll
                    for (int q = 0; q < 4; ++q) {
                        a0 += w[0][c][q] * sv[q];
                        a1 += w[1][c][q] * sv[q];
                        a2 += w[2][c][q] * sv[q];
                        a3 += w[3][c][q] * sv[q];
                    }
                }
            }
            float c_ = wave_reduce4(a0, a1, a2, a3, lane);
            if (lane < 4) red[wave][lane] = c_;
            __syncthreads();
            // ---- publish step i (tag i+1) ----
            if (wave == 0) {
                float sn = 0.f;
                if (lane < 16) {
                    int p2 = (lane >> 2) << 1;
                    float val = red[p2][lane & 3] + red[p2 + 1][lane & 3] + bias;
                    float xi = tanhf(val);
                    sn = (1.f - LEAKF) * s_old + LEAKF * xi;
                    s_old = sn;
                }
                publish16(sn, lane, bid, i & 1, (u32)(i + 1), comm);
            }
        }

        // ---- off critical path: readout y[i-1] ----
        {
            float xv = x[(size_t)(i - 1) * DIN + tid];
            float y0 = wout_lds[tid] * xv;
            float y1 = wout_lds[NINT + tid] * xv;
#pragma unroll
            for (int j = 0; j < 8; ++j) {
                float sv = s_lds[tid + j * NTHR];
                y0 += wout_lds[DIN + tid + j * NTHR] * sv;
                y1 += wout_lds[NINT + DIN + tid + j * NTHR] * sv;
            }
#pragma unroll
            for (int m = 32; m >= 1; m >>= 1) {
                y0 += __shfl_xor(y0, m);
                y1 += __shfl_xor(y1, m);
            }
            if (lane == 0) { red2[wave][0] = y0; red2[wave][1] = y1; }
            __syncthreads();   // also protects s_lds before next staging
            if (tid < 2) {
                float s = 0.f;
#pragma unroll
                for (int wv = 0; wv < 8; ++wv) s += red2[wv][tid];
                y[(size_t)(i - 1) * DOUT + (bid << 1) + tid] = s + wb;
            }
        }

        // ---- off critical path: proj(i+1) ----
        if (i + 1 < T_STEPS) {
            f32x4 xv = *(const f32x4*)(x + (size_t)(i + 1) * DIN + (half << 8) + (lane << 2));
            a0 = a1 = a2 = a3 = 0.f;
#pragma unroll
            for (int q = 0; q < 4; ++q) {
                a0 += win[0][q] * xv[q];
                a1 += win[1][q] * xv[q];
                a2 += win[2][q] * xv[q];
                a3 += win[3][q] * xv[q];
            }
        }
    }
}

extern "C" void kernel_launch(void* const* d_in, const int* in_sizes, int n_in,
                              void* d_out, int out_size, void* d_ws, size_t ws_size,
                              hipStream_t stream) {
    const float* x      = (const float*)d_in[0];
    const float* Win_w  = (const float*)d_in[1];
    const float* Win_b  = (const float*)d_in[2];
    const float* Wres_w = (const float*)d_in[3];
    const float* Wout_w = (const float*)d_in[4];
    const float* Wout_b = (const float*)d_in[5];
    float* yp = (float*)d_out;

    u32x4* comm = (u32x4*)d_ws;   // 2 * 2048 slots * 16 B = 64 KB

    hipMemsetAsync(d_ws, 0, 2 * NSLOT * sizeof(u32x4), stream);

    void* args[] = { (void*)&x, (void*)&Win_w, (void*)&Win_b, (void*)&Wres_w,
                     (void*)&Wout_w, (void*)&Wout_b, (void*)&yp, (void*)&comm };
    hipLaunchCooperativeKernel((void*)esn_fused, dim3(NBLK), dim3(NTHR),
                               args, 0, stream);
}

// Round 4
// 12168.366 us; speedup vs baseline: 10.7016x; 1.0254x over previous
//
#include <hip/hip_runtime.h>

#define T_STEPS 4096
#define DIN     512
#define R_DIM   4096
#define DOUT    512
#define NINT    (R_DIM + DIN)   // 4608
#define NBLK    256
#define NTHR    512
#define NSLOT   2048            // 16B LL slots per buffer; slot s = rows {2s,2s+1}
#define LEAKF   0.9f

typedef float f32x4 __attribute__((ext_vector_type(4)));
typedef unsigned int u32;
typedef u32 u32x4 __attribute__((ext_vector_type(4)));

// Butterfly reduce of TWO values across 64 lanes (7 shuffle+merge steps).
// Returns: even lanes hold full sum of a0, odd lanes full sum of a1.
__device__ __forceinline__ float wave_reduce2(float a0, float a1, int lane)
{
    a0 += __shfl_xor(a0, 1);
    a1 += __shfl_xor(a1, 1);
    float b = (lane & 1) ? a1 : a0;
    b += __shfl_xor(b, 2);
    b += __shfl_xor(b, 4);
    b += __shfl_xor(b, 8);
    b += __shfl_xor(b, 16);
    b += __shfl_xor(b, 32);
    return b;
}

// ---------------------------------------------------------------------------
// Persistent fused ESN. 256 blocks x 512 threads (cooperative, 1 block/CU).
// Block b owns rows [16b,16b+16); wave w owns rows {16b+2w, 16b+2w+1} over the
// FULL K range -> after the in-wave reduce the wave publishes its own LL slot
// (no cross-wave reduce, no producer-side syncthreads on the critical path).
// LL slot = {s_even, tag, s_odd, tag}, tag = step+1, double-buffered by step
// parity. Consumer poll = single round trip (all 64B at once).
// ---------------------------------------------------------------------------
__global__ __launch_bounds__(NTHR, 2) void esn_fused(
    const float* __restrict__ x,       // (T, DIN)
    const float* __restrict__ Win_w,   // (R, DIN)
    const float* __restrict__ Win_b,   // (R)
    const float* __restrict__ Wres,    // (R, R)
    const float* __restrict__ Wout_w,  // (DOUT, NINT)
    const float* __restrict__ Wout_b,  // (DOUT)
    float* __restrict__ y,             // (T, DOUT)
    u32x4* __restrict__ comm)          // 2 * NSLOT slots (d_ws)
{
    const int tid  = threadIdx.x;
    const int wave = tid >> 6;
    const int lane = tid & 63;
    const int bid  = blockIdx.x;
    const int row_e = (bid << 4) + (wave << 1);   // even row owned by this wave

    __shared__ float s_lds[R_DIM];          // 16 KB: s_{i-1}
    __shared__ float wout_lds[2 * NINT];    // 36.9 KB: this block's 2 Wout rows
    __shared__ float red2[8][2];

    // ---- one-time staging ----
    {
        const float* wsrc = Wout_w + (size_t)(bid << 1) * NINT;
        for (int idx = tid; idx < 2 * NINT; idx += NTHR)
            wout_lds[idx] = wsrc[idx];
    }
    const float wb = (tid < 2) ? Wout_b[(bid << 1) + tid] : 0.f;

    // Wres rows in registers: w[r][c] = Wres[row_e+r][lane*4 + c*256 .. +3]
    f32x4 w[2][16];
    {
        const float* wp = Wres + (size_t)row_e * R_DIM + (lane << 2);
#pragma unroll
        for (int r = 0; r < 2; ++r)
#pragma unroll
            for (int c = 0; c < 16; ++c)
                w[r][c] = *(const f32x4*)(wp + (size_t)r * R_DIM + (c << 8));
    }
    f32x4 win[2][2];
    {
        const float* ip = Win_w + (size_t)row_e * DIN + (lane << 2);
#pragma unroll
        for (int r = 0; r < 2; ++r)
#pragma unroll
            for (int c = 0; c < 2; ++c)
                win[r][c] = *(const f32x4*)(ip + (size_t)r * DIN + (c << 8));
    }
    const float bias_e = Win_b[row_e];
    const float bias_o = Win_b[row_e + 1];
    float s_old_e = 0.f, s_old_o = 0.f;

    float a0, a1;

#define PROJ(xrow)                                                        \
    {                                                                     \
        f32x4 xv0 = *(const f32x4*)((xrow) + (lane << 2));                \
        f32x4 xv1 = *(const f32x4*)((xrow) + 256 + (lane << 2));          \
        a0 = 0.f; a1 = 0.f;                                               \
        _Pragma("unroll")                                                 \
        for (int q = 0; q < 4; ++q) {                                     \
            a0 += win[0][0][q] * xv0[q] + win[0][1][q] * xv1[q];          \
            a1 += win[1][0][q] * xv0[q] + win[1][1][q] * xv1[q];          \
        }                                                                 \
    }

    // ---------------- step 0: s0 = tanh(Win x0 + b), tag 1, buf 0 ----------
    {
        PROJ(x);
        float b = wave_reduce2(a0, a1, lane);
        float se = __shfl(b, 0) + bias_e;
        float so = __shfl(b, 1) + bias_o;
        float sn_e = tanhf(se);
        float sn_o = tanhf(so);
        s_old_e = sn_e; s_old_o = sn_o;
        if (lane == 0) {
            u32x4 pkt;
            pkt.x = __float_as_uint(sn_e); pkt.y = 1u;
            pkt.z = __float_as_uint(sn_o); pkt.w = 1u;
            u32x4* dst = comm + (bid << 3) + wave;
            asm volatile("global_store_dwordx4 %0, %1, off sc0 sc1"
                         :: "v"(dst), "v"(pkt) : "memory");
        }
    }
    PROJ(x + DIN);   // proj(1)

    for (int i = 1; i <= T_STEPS; ++i) {
        // ---- stage s_{i-1}: single-round-trip LL poll, write to LDS ----
        {
            const u32x4* src = comm + (((i - 1) & 1) * NSLOT) + (tid << 2);
            const u32 tag = (u32)i;
            u32x4 q0, q1, q2, q3;
            for (;;) {
                asm volatile("global_load_dwordx4 %0, %4, off sc0 sc1\n\t"
                             "global_load_dwordx4 %1, %5, off sc0 sc1\n\t"
                             "global_load_dwordx4 %2, %6, off sc0 sc1\n\t"
                             "global_load_dwordx4 %3, %7, off sc0 sc1\n\t"
                             "s_waitcnt vmcnt(0)"
                             : "=&v"(q0), "=&v"(q1), "=&v"(q2), "=&v"(q3)
                             : "v"(src), "v"(src + 1), "v"(src + 2), "v"(src + 3)
                             : "memory");
                u32 ok = (q0.y == tag) & (q0.w == tag) & (q1.y == tag) &
                         (q1.w == tag) & (q2.y == tag) & (q2.w == tag) &
                         (q3.y == tag) & (q3.w == tag);
                if (ok) break;
                __builtin_amdgcn_s_sleep(1);
            }
            f32x4 lo, hi;
            lo[0] = __uint_as_float(q0.x); lo[1] = __uint_as_float(q0.z);
            lo[2] = __uint_as_float(q1.x); lo[3] = __uint_as_float(q1.z);
            hi[0] = __uint_as_float(q2.x); hi[1] = __uint_as_float(q2.z);
            hi[2] = __uint_as_float(q3.x); hi[3] = __uint_as_float(q3.z);
            *(f32x4*)&s_lds[tid << 3] = lo;
            *(f32x4*)&s_lds[(tid << 3) + 4] = hi;
        }
        __syncthreads();

        if (i < T_STEPS) {
            // ---- matvec: weights in regs, s from LDS (16 x b128) ----
            const f32x4* s4 = (const f32x4*)s_lds + lane;
#pragma unroll
            for (int c = 0; c < 16; ++c) {
                f32x4 sv = s4[c << 6];
#pragma unroll
                for (int q = 0; q < 4; ++q) {
                    a0 += w[0][c][q] * sv[q];
                    a1 += w[1][c][q] * sv[q];
                }
            }
            float b = wave_reduce2(a0, a1, lane);
            float se = __shfl(b, 0) + bias_e;
            float so = __shfl(b, 1) + bias_o;
            float sn_e = (1.f - LEAKF) * s_old_e + LEAKF * tanhf(se);
            float sn_o = (1.f - LEAKF) * s_old_o + LEAKF * tanhf(so);
            s_old_e = sn_e; s_old_o = sn_o;
            if (lane == 0) {
                u32 tag2 = (u32)(i + 1);
                u32x4 pkt;
                pkt.x = __float_as_uint(sn_e); pkt.y = tag2;
                pkt.z = __float_as_uint(sn_o); pkt.w = tag2;
                u32x4* dst = comm + ((i & 1) * NSLOT) + (bid << 3) + wave;
                asm volatile("global_store_dwordx4 %0, %1, off sc0 sc1"
                             :: "v"(dst), "v"(pkt) : "memory");
            }
        }

        // ---- off critical path: readout y[i-1] partials ----
        {
            float xv = x[(size_t)(i - 1) * DIN + tid];
            float y0 = wout_lds[tid] * xv;
            float y1 = wout_lds[NINT + tid] * xv;
#pragma unroll
            for (int j = 0; j < 8; ++j) {
                float sv = s_lds[tid + j * NTHR];
                y0 += wout_lds[DIN + tid + j * NTHR] * sv;
                y1 += wout_lds[NINT + DIN + tid + j * NTHR] * sv;
            }
            float b = wave_reduce2(y0, y1, lane);
            if (lane < 2) red2[wave][lane] = b;
        }

        // ---- off critical path: proj(i+1) ----
        if (i + 1 < T_STEPS) PROJ(x + (size_t)(i + 1) * DIN);

        __syncthreads();   // red2 complete; s_lds consumption done

        if (tid < 2) {
            float s = 0.f;
#pragma unroll
            for (int wv = 0; wv < 8; ++wv) s += red2[wv][tid];
            y[(size_t)(i - 1) * DOUT + (bid << 1) + tid] = s + wb;
        }
    }
#undef PROJ
}

extern "C" void kernel_launch(void* const* d_in, const int* in_sizes, int n_in,
                              void* d_out, int out_size, void* d_ws, size_t ws_size,
                              hipStream_t stream) {
    const float* x      = (const float*)d_in[0];
    const float* Win_w  = (const float*)d_in[1];
    const float* Win_b  = (const float*)d_in[2];
    const float* Wres_w = (const float*)d_in[3];
    const float* Wout_w = (const float*)d_in[4];
    const float* Wout_b = (const float*)d_in[5];
    float* yp = (float*)d_out;

    u32x4* comm = (u32x4*)d_ws;   // 2 * 2048 slots * 16 B = 64 KB

    hipMemsetAsync(d_ws, 0, 2 * NSLOT * sizeof(u32x4), stream);

    void* args[] = { (void*)&x, (void*)&Win_w, (void*)&Win_b, (void*)&Wres_w,
                     (void*)&Wout_w, (void*)&Wout_b, (void*)&yp, (void*)&comm };
    hipLaunchCooperativeKernel((void*)esn_fused, dim3(NBLK), dim3(NTHR),
                               args, 0, stream);
}